// Round 1
// baseline (740.582 us; speedup 1.0000x reference)
//
#include <hip/hip_runtime.h>
#include <math.h>

// ---------------- helpers ----------------

__device__ __forceinline__ float wave_sum(float v) {
#pragma unroll
    for (int o = 32; o > 0; o >>= 1) v += __shfl_down(v, o);
    return v;
}

// blockDim.x == 256 only
__device__ __forceinline__ float block_sum256(float v, float* red) {
    v = wave_sum(v);
    int t = threadIdx.x;
    if ((t & 63) == 0) red[t >> 6] = v;
    __syncthreads();
    float r = red[0] + red[1] + red[2] + red[3];
    __syncthreads();
    return r;
}

__device__ __forceinline__ unsigned fenc(float f) {
    unsigned u = __float_as_uint(f);
    return (u & 0x80000000u) ? ~u : (u | 0x80000000u);
}
__device__ __forceinline__ float fdec(unsigned u) {
    return (u & 0x80000000u) ? __uint_as_float(u & 0x7fffffffu) : __uint_as_float(~u);
}

// ---------------- init ----------------
// ws float layout:
// 0 recon_sum, 1 abs1, 2 abs2, 3 ent1, 4 ent2, 5 sl_sum, 6 jac_sum
// 7 min1(u),8 max1(u),9 min2(u),10 max2(u)
// 16..271 hist1(int), 272..527 hist2(int)
// 528..1039 rnorm[512]
// 1040 e[512*256], 132112 A[512*256], 263184 E[65536]

__global__ void init_kernel(float* wsf, unsigned* wsu, int* wsi) {
    int t = threadIdx.x;
    if (t < 7) wsf[t] = 0.f;
    if (t == 7 || t == 9) wsu[t] = 0xFFFFFFFFu;   // mins
    if (t == 8 || t == 10) wsu[t] = 0u;           // maxs
    wsi[16 + t] = 0;
    wsi[272 + t] = 0;
}

// ---------------- recon ----------------
__global__ void recon_kernel(const float4* __restrict__ o, const float4* __restrict__ im,
                             int n4, float* acc) {
    __shared__ float red[4];
    float s = 0.f;
    for (int i = blockIdx.x * blockDim.x + threadIdx.x; i < n4; i += gridDim.x * blockDim.x) {
        float4 a = o[i], b = im[i];
        float dx = a.x - b.x, dy = a.y - b.y, dz = a.z - b.z, dw = a.w - b.w;
        s += dx * dx + dy * dy + dz * dz + dw * dw;
    }
    float tot = block_sum256(s, red);
    if (threadIdx.x == 0) atomicAdd(acc, tot);
}

// ---------------- abs-sum + min/max ----------------
__global__ void absmm_kernel(const float4* __restrict__ x, int n4,
                             float* absAcc, unsigned* mnAcc, unsigned* mxAcc) {
    __shared__ float red[4];
    __shared__ float rmn[4], rmx[4];
    float s = 0.f, mn = INFINITY, mx = -INFINITY;
    for (int i = blockIdx.x * blockDim.x + threadIdx.x; i < n4; i += gridDim.x * blockDim.x) {
        float4 a = x[i];
        s += fabsf(a.x) + fabsf(a.y) + fabsf(a.z) + fabsf(a.w);
        mn = fminf(mn, fminf(fminf(a.x, a.y), fminf(a.z, a.w)));
        mx = fmaxf(mx, fmaxf(fmaxf(a.x, a.y), fmaxf(a.z, a.w)));
    }
    float tot = block_sum256(s, red);
#pragma unroll
    for (int o = 32; o > 0; o >>= 1) {
        mn = fminf(mn, __shfl_down(mn, o));
        mx = fmaxf(mx, __shfl_down(mx, o));
    }
    int t = threadIdx.x;
    if ((t & 63) == 0) { rmn[t >> 6] = mn; rmx[t >> 6] = mx; }
    __syncthreads();
    if (t == 0) {
        atomicAdd(absAcc, tot);
        float m1 = fminf(fminf(rmn[0], rmn[1]), fminf(rmn[2], rmn[3]));
        float m2 = fmaxf(fmaxf(rmx[0], rmx[1]), fmaxf(rmx[2], rmx[3]));
        atomicMin(mnAcc, fenc(m1));
        atomicMax(mxAcc, fenc(m2));
    }
}

// ---------------- histogram ----------------
__global__ void hist_kernel(const float4* __restrict__ x, int n4,
                            const unsigned* mm, int* hist) {
    __shared__ int hl[256];
    hl[threadIdx.x] = 0;
    __syncthreads();
    float mn = fdec(mm[0]), mx = fdec(mm[1]);
    float inv = 256.f / (mx - mn + 1e-8f);
    for (int i = blockIdx.x * blockDim.x + threadIdx.x; i < n4; i += gridDim.x * blockDim.x) {
        float4 a = x[i];
        int b0 = min(max((int)floorf((a.x - mn) * inv), 0), 255);
        int b1 = min(max((int)floorf((a.y - mn) * inv), 0), 255);
        int b2 = min(max((int)floorf((a.z - mn) * inv), 0), 255);
        int b3 = min(max((int)floorf((a.w - mn) * inv), 0), 255);
        atomicAdd(&hl[b0], 1);
        atomicAdd(&hl[b1], 1);
        atomicAdd(&hl[b2], 1);
        atomicAdd(&hl[b3], 1);
    }
    __syncthreads();
    if (hl[threadIdx.x]) atomicAdd(&hist[threadIdx.x], hl[threadIdx.x]);
}

// ---------------- entropy ----------------
__global__ void entropy_kernel(const int* h1, const int* h2, float* out, float n1, float n2) {
    __shared__ float red[4];
    int t = threadIdx.x;
    float p1 = (float)h1[t] / n1;
    float p2 = (float)h2[t] / n2;
    float e1 = -p1 * log2f(p1 + 1e-8f);
    float e2 = -p2 * log2f(p2 + 1e-8f);
    float s1 = block_sum256(e1, red);
    float s2 = block_sum256(e2, red);
    if (t == 0) { out[0] = s1; out[1] = s2; }
}

// ---------------- row norms (reciprocal) ----------------
__global__ void norm_kernel(const float4* __restrict__ fo, const float4* __restrict__ fr,
                            float* rnorm) {
    __shared__ float red[4];
    int r = blockIdx.x;  // 0..511
    const float4* f = (r < 256) ? (fo + (size_t)r * 128) : (fr + (size_t)(r - 256) * 128);
    float s = 0.f;
    if (threadIdx.x < 128) {
        float4 a = f[threadIdx.x];
        s = a.x * a.x + a.y * a.y + a.z * a.z + a.w * a.w;
    }
    float tot = block_sum256(s, red);
    if (threadIdx.x == 0) rnorm[r] = 1.0f / sqrtf(tot);
}

// ---------------- encoder: e = relu(LN(f@W1+b1))@W2+b2 ; A = e @ W3part ----------------
__global__ void encoder_kernel(const float* __restrict__ f_orig, const float* __restrict__ f_recon,
                               const float* __restrict__ W1, const float* __restrict__ b1,
                               const float* __restrict__ g1, const float* __restrict__ be1,
                               const float* __restrict__ W2, const float* __restrict__ b2,
                               const float* __restrict__ W3,
                               float* __restrict__ eAll, float* __restrict__ Aall) {
    int r = blockIdx.x;  // 0..511
    int t = threadIdx.x; // 0..255
    const float* f = (r < 256) ? (f_orig + (size_t)r * 512) : (f_recon + (size_t)(r - 256) * 512);
    const float* W3p = (r < 256) ? W3 : (W3 + 256 * 256);
    __shared__ float fs[512];
    __shared__ float hs[256];
    __shared__ float es[256];
    __shared__ float red[4];
    fs[t] = f[t];
    fs[t + 256] = f[t + 256];
    __syncthreads();
    float x = b1[t];
    for (int k = 0; k < 512; ++k) x += fs[k] * W1[k * 256 + t];
    float s1 = block_sum256(x, red);
    float s2 = block_sum256(x * x, red);
    float mean = s1 * (1.f / 256.f);
    float var = s2 * (1.f / 256.f) - mean * mean;
    float rstd = rsqrtf(var + 1e-5f);
    float hn = (x - mean) * rstd * g1[t] + be1[t];
    hs[t] = fmaxf(hn, 0.f);
    __syncthreads();
    float e = b2[t];
    for (int k = 0; k < 256; ++k) e += hs[k] * W2[k * 256 + t];
    eAll[(size_t)r * 256 + t] = e;
    es[t] = e;
    __syncthreads();
    float a = 0.f;
    for (int k = 0; k < 256; ++k) a += es[k] * W3p[k * 256 + t];
    Aall[(size_t)r * 256 + t] = a;
}

// ---------------- top-k jaccard ----------------
__global__ void topk_kernel(const float4* __restrict__ fo, const float4* __restrict__ fr,
                            const float* __restrict__ rnorm, float* jacAcc) {
    int i = blockIdx.x, t = threadIdx.x;
    __shared__ float4 fis[128];
    __shared__ float sv[256];
    __shared__ int si[256];
    __shared__ int O[5], R[5];
    for (int pass = 0; pass < 2; ++pass) {
        const float4* f = pass ? fr : fo;
        const float* rn = pass ? (rnorm + 256) : rnorm;
        if (t < 128) fis[t] = f[(size_t)i * 128 + t];
        __syncthreads();
        float dot = 0.f;
        const float4* frow = f + (size_t)t * 128;
        for (int k = 0; k < 128; ++k) {
            float4 a = fis[k], b = frow[k];
            dot += a.x * b.x + a.y * b.y + a.z * b.z + a.w * b.w;
        }
        float simv = dot * rn[i] * rn[t];
        if (t == i) simv = -INFINITY;
        int chosen = 0;
        for (int r5 = 0; r5 < 5; ++r5) {
            sv[t] = chosen ? -INFINITY : simv;
            si[t] = t;
            __syncthreads();
            for (int s = 128; s > 0; s >>= 1) {
                if (t < s) {
                    if (sv[t + s] > sv[t] || (sv[t + s] == sv[t] && si[t + s] < si[t])) {
                        sv[t] = sv[t + s];
                        si[t] = si[t + s];
                    }
                }
                __syncthreads();
            }
            int w = si[0];
            if (t == w) chosen = 1;
            if (t == 0) { if (pass) R[r5] = w; else O[r5] = w; }
            __syncthreads();
        }
        __syncthreads();
    }
    if (t == 0) {
        int inter = 0;
#pragma unroll
        for (int a = 0; a < 5; ++a)
#pragma unroll
            for (int b = 0; b < 5; ++b) inter += (O[a] == R[b]);
        float fi2 = (float)inter;
        float jac = fi2 / (10.f - fi2 + 1e-8f);
        atomicAdd(jacAcc, jac);
    }
}

// ---------------- energy pairs ----------------
// E[i,j] = W5 . relu(W4^T . relu(LN(A1[i]+A2[j]+(e1[i]*e2[j])@W3c + b3)*g3+be3) + b4) + b5
__global__ void energy_kernel(const float* __restrict__ eAll, const float* __restrict__ Aall,
                              const float* __restrict__ W3c, const float* __restrict__ b3,
                              const float* __restrict__ g3, const float* __restrict__ be3,
                              const float* __restrict__ W4, const float* __restrict__ b4,
                              const float* __restrict__ W5, const float* __restrict__ b5,
                              float* __restrict__ E) {
    const float* e1 = eAll;
    const float* e2 = eAll + 65536;
    const float* A1 = Aall;
    const float* A2 = Aall + 65536;
    int i = blockIdx.x >> 2;
    int jbase = (blockIdx.x & 3) << 6;
    int t = threadIdx.x;
    __shared__ float e1s[256], A1s[256];
    __shared__ float v[16][256];
    __shared__ float hs[256];
    __shared__ float part[256];
    __shared__ float red[8];
    e1s[t] = e1[(size_t)i * 256 + t];
    A1s[t] = A1[(size_t)i * 256 + t];
    float b3t = b3[t], g3t = g3[t], be3t = be3[t];
    float w5t = (t < 128) ? W5[t] : 0.f;
    float b4t = (t < 128) ? b4[t] : 0.f;
    float b5v = b5[0];
    __syncthreads();
    for (int jb = 0; jb < 4; ++jb) {
        int j0 = jbase + (jb << 4);
#pragma unroll
        for (int jj = 0; jj < 16; ++jj)
            v[jj][t] = e1s[t] * e2[(size_t)(j0 + jj) * 256 + t];
        __syncthreads();
        float acc[16];
#pragma unroll
        for (int jj = 0; jj < 16; ++jj) acc[jj] = 0.f;
        for (int k = 0; k < 256; k += 4) {
            float w0 = W3c[(k + 0) * 256 + t];
            float w1 = W3c[(k + 1) * 256 + t];
            float w2 = W3c[(k + 2) * 256 + t];
            float w3 = W3c[(k + 3) * 256 + t];
#pragma unroll
            for (int jj = 0; jj < 16; ++jj) {
                float4 vv = *reinterpret_cast<const float4*>(&v[jj][k]);
                acc[jj] += vv.x * w0 + vv.y * w1 + vv.z * w2 + vv.w * w3;
            }
        }
        __syncthreads();
        for (int jj = 0; jj < 16; ++jj) {
            int j = j0 + jj;
            float tv = acc[jj] + A1s[t] + A2[(size_t)j * 256 + t] + b3t;
            float s1 = wave_sum(tv);
            float s2 = wave_sum(tv * tv);
            if ((t & 63) == 0) { red[t >> 6] = s1; red[4 + (t >> 6)] = s2; }
            __syncthreads();
            float mean = (red[0] + red[1] + red[2] + red[3]) * (1.f / 256.f);
            float var = (red[4] + red[5] + red[6] + red[7]) * (1.f / 256.f) - mean * mean;
            float rstd = rsqrtf(var + 1e-5f);
            float hv = fmaxf((tv - mean) * rstd * g3t + be3t, 0.f);
            hs[t] = hv;
            __syncthreads();
            // W4: [256,128]; split n-range across two half-warustes of threads
            int m = t & 127, half = t >> 7;
            float p = 0.f;
            const float* w4p = W4 + (size_t)(half * 128) * 128 + m;
            const float* hp = hs + half * 128;
#pragma unroll 4
            for (int n = 0; n < 128; ++n) p += hp[n] * w4p[(size_t)n * 128];
            part[t] = p;
            __syncthreads();
            float ep = 0.f;
            if (t < 128) {
                float h2 = fmaxf(part[t] + part[t + 128] + b4t, 0.f);
                ep = h2 * w5t;
            }
            ep = wave_sum(ep);
            if (t == 0) red[0] = ep;
            if (t == 64) red[1] = ep;
            __syncthreads();
            if (t == 0) E[(size_t)i * 256 + j] = red[0] + red[1] + b5v;
            __syncthreads();
        }
    }
}

// ---------------- margin loss ----------------
__global__ void margin_kernel(const float* __restrict__ E, float* slAcc) {
    __shared__ float red[4];
    int i = blockIdx.x, t = threadIdx.x;
    float diag = E[(size_t)i * 256 + i];
    float l = (t == i) ? 0.f : fmaxf(1.f + E[(size_t)i * 256 + t] - diag, 0.f);
    float tot = block_sum256(l, red);
    if (t == 0) atomicAdd(slAcc, tot);
}

// ---------------- finalize ----------------
__global__ void finalize_kernel(const float* wsf, float* out) {
    if (threadIdx.x == 0 && blockIdx.x == 0) {
        float recon = wsf[0] / 3145728.f;
        float sp = 0.5f * (wsf[1] / 4194304.f + wsf[2] / 2097152.f);
        float en = 0.5f * (wsf[3] + wsf[4]);
        float compress = sp + 0.1f * en;
        float sl = wsf[5] / (256.f * 255.f);
        float nl = 1.f - wsf[6] / 256.f;
        float energy = sl + 0.3f * nl;
        float total = recon + 0.01f * compress + 0.1f * energy;
        out[0] = total;
        out[1] = recon;
        out[2] = energy;
        out[3] = compress;
    }
}

// ---------------- launch ----------------
extern "C" void kernel_launch(void* const* d_in, const int* in_sizes, int n_in,
                              void* d_out, int out_size, void* d_ws, size_t ws_size,
                              hipStream_t stream) {
    const float* outputs = (const float*)d_in[0];
    const float* images  = (const float*)d_in[1];
    const float* f_orig  = (const float*)d_in[2];
    const float* f_recon = (const float*)d_in[3];
    const float* cf1 = (const float*)d_in[4];
    const float* cf2 = (const float*)d_in[5];
    const float* W1 = (const float*)d_in[6];
    const float* b1 = (const float*)d_in[7];
    const float* g1 = (const float*)d_in[8];
    const float* be1 = (const float*)d_in[9];
    const float* W2 = (const float*)d_in[10];
    const float* b2 = (const float*)d_in[11];
    const float* W3 = (const float*)d_in[12];
    const float* b3 = (const float*)d_in[13];
    const float* g3 = (const float*)d_in[14];
    const float* be3 = (const float*)d_in[15];
    const float* W4 = (const float*)d_in[16];
    const float* b4 = (const float*)d_in[17];
    const float* W5 = (const float*)d_in[18];
    const float* b5 = (const float*)d_in[19];

    float* wsf = (float*)d_ws;
    unsigned* wsu = (unsigned*)d_ws;
    int* wsi = (int*)d_ws;
    float* out = (float*)d_out;

    float* rnorm = wsf + 528;
    float* eAll = wsf + 1040;
    float* Aall = wsf + 132112;
    float* Emat = wsf + 263184;

    hipLaunchKernelGGL(init_kernel, dim3(1), dim3(256), 0, stream, wsf, wsu, wsi);
    hipLaunchKernelGGL(recon_kernel, dim3(512), dim3(256), 0, stream,
                       (const float4*)outputs, (const float4*)images, 786432, wsf + 0);
    hipLaunchKernelGGL(absmm_kernel, dim3(512), dim3(256), 0, stream,
                       (const float4*)cf1, 1048576, wsf + 1, wsu + 7, wsu + 8);
    hipLaunchKernelGGL(absmm_kernel, dim3(512), dim3(256), 0, stream,
                       (const float4*)cf2, 524288, wsf + 2, wsu + 9, wsu + 10);
    hipLaunchKernelGGL(hist_kernel, dim3(512), dim3(256), 0, stream,
                       (const float4*)cf1, 1048576, wsu + 7, wsi + 16);
    hipLaunchKernelGGL(hist_kernel, dim3(512), dim3(256), 0, stream,
                       (const float4*)cf2, 524288, wsu + 9, wsi + 272);
    hipLaunchKernelGGL(entropy_kernel, dim3(1), dim3(256), 0, stream,
                       wsi + 16, wsi + 272, wsf + 3, 4194304.f, 2097152.f);
    hipLaunchKernelGGL(norm_kernel, dim3(512), dim3(256), 0, stream,
                       (const float4*)f_orig, (const float4*)f_recon, rnorm);
    hipLaunchKernelGGL(encoder_kernel, dim3(512), dim3(256), 0, stream,
                       f_orig, f_recon, W1, b1, g1, be1, W2, b2, W3, eAll, Aall);
    hipLaunchKernelGGL(topk_kernel, dim3(256), dim3(256), 0, stream,
                       (const float4*)f_orig, (const float4*)f_recon, rnorm, wsf + 6);
    hipLaunchKernelGGL(energy_kernel, dim3(1024), dim3(256), 0, stream,
                       eAll, Aall, W3 + 512 * 256, b3, g3, be3, W4, b4, W5, b5, Emat);
    hipLaunchKernelGGL(margin_kernel, dim3(256), dim3(256), 0, stream, Emat, wsf + 5);
    hipLaunchKernelGGL(finalize_kernel, dim3(1), dim3(1), 0, stream, wsf, out);
}

// Round 2
// 323.563 us; speedup vs baseline: 2.2888x; 2.2888x over previous
//
#include <hip/hip_runtime.h>
#include <math.h>

typedef __attribute__((ext_vector_type(8))) short short8;
typedef __attribute__((ext_vector_type(4))) float f32x4;

// ---------------- helpers ----------------

__device__ __forceinline__ float wave_sum(float v) {
#pragma unroll
    for (int o = 32; o > 0; o >>= 1) v += __shfl_down(v, o);
    return v;
}

// blockDim.x == 256 only
__device__ __forceinline__ float block_sum256(float v, float* red) {
    v = wave_sum(v);
    int t = threadIdx.x;
    if ((t & 63) == 0) red[t >> 6] = v;
    __syncthreads();
    float r = red[0] + red[1] + red[2] + red[3];
    __syncthreads();
    return r;
}

__device__ __forceinline__ unsigned fenc(float f) {
    unsigned u = __float_as_uint(f);
    return (u & 0x80000000u) ? ~u : (u | 0x80000000u);
}
__device__ __forceinline__ float fdec(unsigned u) {
    return (u & 0x80000000u) ? __uint_as_float(u & 0x7fffffffu) : __uint_as_float(~u);
}

__device__ __forceinline__ ushort f2bf(float f) {
    unsigned u = __float_as_uint(f);
    unsigned r = (u + 0x7fffu + ((u >> 16) & 1u)) >> 16;
    return (ushort)r;
}

// ---------------- init ----------------
// ws float layout:
// 0 recon_sum, 1 abs1, 2 abs2, 3 ent1, 4 ent2, 5 sl_sum, 6 jac_sum
// 7 min1(u),8 max1(u),9 min2(u),10 max2(u)
// 16..271 hist1(int), 272..527 hist2(int)
// 528..1039 rnorm[512]
// 1040 e[512*256], 132112 A[512*256], 263184 E[65536]
// 328720 W3pack (65536 bf16 = 32768 floats), 361488 W4pack (32768 bf16 = 16384 floats)

__global__ void init_kernel(float* wsf, unsigned* wsu, int* wsi) {
    int t = threadIdx.x;
    if (t < 7) wsf[t] = 0.f;
    if (t == 7 || t == 9) wsu[t] = 0xFFFFFFFFu;   // mins
    if (t == 8 || t == 10) wsu[t] = 0u;           // maxs
    wsi[16 + t] = 0;
    wsi[272 + t] = 0;
}

// ---------------- recon ----------------
__global__ void recon_kernel(const float4* __restrict__ o, const float4* __restrict__ im,
                             int n4, float* acc) {
    __shared__ float red[4];
    float s = 0.f;
    for (int i = blockIdx.x * blockDim.x + threadIdx.x; i < n4; i += gridDim.x * blockDim.x) {
        float4 a = o[i], b = im[i];
        float dx = a.x - b.x, dy = a.y - b.y, dz = a.z - b.z, dw = a.w - b.w;
        s += dx * dx + dy * dy + dz * dz + dw * dw;
    }
    float tot = block_sum256(s, red);
    if (threadIdx.x == 0) atomicAdd(acc, tot);
}

// ---------------- abs-sum + min/max ----------------
__global__ void absmm_kernel(const float4* __restrict__ x, int n4,
                             float* absAcc, unsigned* mnAcc, unsigned* mxAcc) {
    __shared__ float red[4];
    __shared__ float rmn[4], rmx[4];
    float s = 0.f, mn = INFINITY, mx = -INFINITY;
    for (int i = blockIdx.x * blockDim.x + threadIdx.x; i < n4; i += gridDim.x * blockDim.x) {
        float4 a = x[i];
        s += fabsf(a.x) + fabsf(a.y) + fabsf(a.z) + fabsf(a.w);
        mn = fminf(mn, fminf(fminf(a.x, a.y), fminf(a.z, a.w)));
        mx = fmaxf(mx, fmaxf(fmaxf(a.x, a.y), fmaxf(a.z, a.w)));
    }
    float tot = block_sum256(s, red);
#pragma unroll
    for (int o = 32; o > 0; o >>= 1) {
        mn = fminf(mn, __shfl_down(mn, o));
        mx = fmaxf(mx, __shfl_down(mx, o));
    }
    int t = threadIdx.x;
    if ((t & 63) == 0) { rmn[t >> 6] = mn; rmx[t >> 6] = mx; }
    __syncthreads();
    if (t == 0) {
        atomicAdd(absAcc, tot);
        float m1 = fminf(fminf(rmn[0], rmn[1]), fminf(rmn[2], rmn[3]));
        float m2 = fmaxf(fmaxf(rmx[0], rmx[1]), fmaxf(rmx[2], rmx[3]));
        atomicMin(mnAcc, fenc(m1));
        atomicMax(mxAcc, fenc(m2));
    }
}

// ---------------- histogram ----------------
__global__ void hist_kernel(const float4* __restrict__ x, int n4,
                            const unsigned* mm, int* hist) {
    __shared__ int hl[256];
    hl[threadIdx.x] = 0;
    __syncthreads();
    float mn = fdec(mm[0]), mx = fdec(mm[1]);
    float inv = 256.f / (mx - mn + 1e-8f);
    for (int i = blockIdx.x * blockDim.x + threadIdx.x; i < n4; i += gridDim.x * blockDim.x) {
        float4 a = x[i];
        int b0 = min(max((int)floorf((a.x - mn) * inv), 0), 255);
        int b1 = min(max((int)floorf((a.y - mn) * inv), 0), 255);
        int b2 = min(max((int)floorf((a.z - mn) * inv), 0), 255);
        int b3 = min(max((int)floorf((a.w - mn) * inv), 0), 255);
        atomicAdd(&hl[b0], 1);
        atomicAdd(&hl[b1], 1);
        atomicAdd(&hl[b2], 1);
        atomicAdd(&hl[b3], 1);
    }
    __syncthreads();
    if (hl[threadIdx.x]) atomicAdd(&hist[threadIdx.x], hl[threadIdx.x]);
}

// ---------------- entropy ----------------
__global__ void entropy_kernel(const int* h1, const int* h2, float* out, float n1, float n2) {
    __shared__ float red[4];
    int t = threadIdx.x;
    float p1 = (float)h1[t] / n1;
    float p2 = (float)h2[t] / n2;
    float e1 = -p1 * log2f(p1 + 1e-8f);
    float e2 = -p2 * log2f(p2 + 1e-8f);
    float s1 = block_sum256(e1, red);
    float s2 = block_sum256(e2, red);
    if (t == 0) { out[0] = s1; out[1] = s2; }
}

// ---------------- row norms (reciprocal) ----------------
__global__ void norm_kernel(const float4* __restrict__ fo, const float4* __restrict__ fr,
                            float* rnorm) {
    __shared__ float red[4];
    int r = blockIdx.x;  // 0..511
    const float4* f = (r < 256) ? (fo + (size_t)r * 128) : (fr + (size_t)(r - 256) * 128);
    float s = 0.f;
    if (threadIdx.x < 128) {
        float4 a = f[threadIdx.x];
        s = a.x * a.x + a.y * a.y + a.z * a.z + a.w * a.w;
    }
    float tot = block_sum256(s, red);
    if (threadIdx.x == 0) rnorm[r] = 1.0f / sqrtf(tot);
}

// ---------------- encoder: e = relu(LN(f@W1+b1))@W2+b2 ; A = e @ W3part ----------------
__global__ void encoder_kernel(const float* __restrict__ f_orig, const float* __restrict__ f_recon,
                               const float* __restrict__ W1, const float* __restrict__ b1,
                               const float* __restrict__ g1, const float* __restrict__ be1,
                               const float* __restrict__ W2, const float* __restrict__ b2,
                               const float* __restrict__ W3,
                               float* __restrict__ eAll, float* __restrict__ Aall) {
    int r = blockIdx.x;  // 0..511
    int t = threadIdx.x; // 0..255
    const float* f = (r < 256) ? (f_orig + (size_t)r * 512) : (f_recon + (size_t)(r - 256) * 512);
    const float* W3p = (r < 256) ? W3 : (W3 + 256 * 256);
    __shared__ float fs[512];
    __shared__ float hs[256];
    __shared__ float es[256];
    __shared__ float red[4];
    fs[t] = f[t];
    fs[t + 256] = f[t + 256];
    __syncthreads();
    float x = b1[t];
    for (int k = 0; k < 512; ++k) x += fs[k] * W1[k * 256 + t];
    float s1 = block_sum256(x, red);
    float s2 = block_sum256(x * x, red);
    float mean = s1 * (1.f / 256.f);
    float var = s2 * (1.f / 256.f) - mean * mean;
    float rstd = rsqrtf(var + 1e-5f);
    float hn = (x - mean) * rstd * g1[t] + be1[t];
    hs[t] = fmaxf(hn, 0.f);
    __syncthreads();
    float e = b2[t];
    for (int k = 0; k < 256; ++k) e += hs[k] * W2[k * 256 + t];
    eAll[(size_t)r * 256 + t] = e;
    es[t] = e;
    __syncthreads();
    float a = 0.f;
    for (int k = 0; k < 256; ++k) a += es[k] * W3p[k * 256 + t];
    Aall[(size_t)r * 256 + t] = a;
}

// ---------------- top-k jaccard ----------------
__global__ void topk_kernel(const float4* __restrict__ fo, const float4* __restrict__ fr,
                            const float* __restrict__ rnorm, float* jacAcc) {
    int i = blockIdx.x, t = threadIdx.x;
    __shared__ float4 fis[128];
    __shared__ float sv[256];
    __shared__ int si[256];
    __shared__ int O[5], R[5];
    for (int pass = 0; pass < 2; ++pass) {
        const float4* f = pass ? fr : fo;
        const float* rn = pass ? (rnorm + 256) : rnorm;
        if (t < 128) fis[t] = f[(size_t)i * 128 + t];
        __syncthreads();
        float dot = 0.f;
        const float4* frow = f + (size_t)t * 128;
        for (int k = 0; k < 128; ++k) {
            float4 a = fis[k], b = frow[k];
            dot += a.x * b.x + a.y * b.y + a.z * b.z + a.w * b.w;
        }
        float simv = dot * rn[i] * rn[t];
        if (t == i) simv = -INFINITY;
        int chosen = 0;
        for (int r5 = 0; r5 < 5; ++r5) {
            sv[t] = chosen ? -INFINITY : simv;
            si[t] = t;
            __syncthreads();
            for (int s = 128; s > 0; s >>= 1) {
                if (t < s) {
                    if (sv[t + s] > sv[t] || (sv[t + s] == sv[t] && si[t + s] < si[t])) {
                        sv[t] = sv[t + s];
                        si[t] = si[t + s];
                    }
                }
                __syncthreads();
            }
            int wIdx = si[0];
            if (t == wIdx) chosen = 1;
            if (t == 0) { if (pass) R[r5] = wIdx; else O[r5] = wIdx; }
            __syncthreads();
        }
        __syncthreads();
    }
    if (t == 0) {
        int inter = 0;
#pragma unroll
        for (int a = 0; a < 5; ++a)
#pragma unroll
            for (int b = 0; b < 5; ++b) inter += (O[a] == R[b]);
        float fi2 = (float)inter;
        float jac = fi2 / (10.f - fi2 + 1e-8f);
        atomicAdd(jacAcc, jac);
    }
}

// ---------------- pack W3c into bf16 B-fragment order ----------------
// slot s in [0,8192): lane=s&63, tt=(s>>6)&15, kk=s>>10
// element jj: B[k= kk*32 + (lane>>4)*8 + jj][t = tt*16 + (lane&15)]
__global__ void pack_w3_kernel(const float* __restrict__ W3c, ushort* __restrict__ W3p) {
    int s = blockIdx.x * 256 + threadIdx.x;   // 0..8191
    int lane = s & 63;
    int tt = (s >> 6) & 15;
    int kk = s >> 10;
    int qq = lane >> 4, nn = lane & 15;
    int tcol = tt * 16 + nn;
    short8 v;
#pragma unroll
    for (int jj = 0; jj < 8; ++jj) {
        int k = kk * 32 + qq * 8 + jj;
        v[jj] = (short)f2bf(W3c[(size_t)k * 256 + tcol]);
    }
    *(short8*)(W3p + (size_t)s * 8) = v;
}

// slot s in [0,4096): lane=s&63, tt=(s>>6)&7, kk=s>>9
__global__ void pack_w4_kernel(const float* __restrict__ W4, ushort* __restrict__ W4p) {
    int s = blockIdx.x * 256 + threadIdx.x;   // 0..4095
    int lane = s & 63;
    int tt = (s >> 6) & 7;
    int kk = s >> 9;
    int qq = lane >> 4, nn = lane & 15;
    int ncol = tt * 16 + nn;
    short8 v;
#pragma unroll
    for (int jj = 0; jj < 8; ++jj) {
        int k = kk * 32 + qq * 8 + jj;
        v[jj] = (short)f2bf(W4[(size_t)k * 128 + ncol]);
    }
    *(short8*)(W4p + (size_t)s * 8) = v;
}

// ---------------- energy pairs via MFMA ----------------
// block = (i, j-quarter); wave w owns j-strip of 16 rows x full 256 cols.
// GEMM1: P = V @ W3c, V[j,k]=e1[i,k]*e2[j,k] (A-frags built on the fly, bf16)
// LN over t per row (quad shfl_xor butterfly), relu -> H (bf16, LDS round-trip)
// GEMM2: G = H @ W4; epilogue relu(G+b4)@W5 + b5 -> E[i,j]
__global__ __launch_bounds__(256) void energy_mfma_kernel(
    const float* __restrict__ eAll, const float* __restrict__ Aall,
    const ushort* __restrict__ W3p, const ushort* __restrict__ W4p,
    const float* __restrict__ b3, const float* __restrict__ g3, const float* __restrict__ be3,
    const float* __restrict__ b4, const float* __restrict__ W5, const float* __restrict__ b5,
    float* __restrict__ E)
{
    int i = blockIdx.x >> 2;
    int jq = blockIdx.x & 3;
    int t = threadIdx.x;
    int w = t >> 6;
    int lane = t & 63;
    int q = lane >> 4;
    int n = lane & 15;
    int jbase = jq * 64 + w * 16;

    __shared__ float comb[256], g3s[256], be3s[256];
    __shared__ uint4 Bst[1024];                        // 16 KB staging buffer
    __shared__ __align__(16) ushort Hs[4][16 * 264];   // per-wave H, padded stride

    const float* e1 = eAll + (size_t)i * 256;
    const float* e2 = eAll + 65536;
    const float* A1 = Aall + (size_t)i * 256;
    const float* A2 = Aall + 65536;

    comb[t] = A1[t] + b3[t];
    g3s[t] = g3[t];
    be3s[t] = be3[t];

    f32x4 acc[16];
#pragma unroll
    for (int x = 0; x < 16; ++x) acc[x] = (f32x4){0.f, 0.f, 0.f, 0.f};

    const float* e2row = e2 + (size_t)(jbase + n) * 256;   // A-frag row (m = lane&15)

    for (int kk = 0; kk < 8; ++kk) {
        __syncthreads();   // prior Bst reads done (also covers comb/g3s on first iter)
        {
            const uint4* src = (const uint4*)(W3p + (size_t)kk * 8192);
#pragma unroll
            for (int x = 0; x < 4; ++x) Bst[t * 4 + x] = src[t * 4 + x];
        }
        int kb = kk * 32 + q * 8;
        float4 ea0 = *(const float4*)(e2row + kb);
        float4 ea1 = *(const float4*)(e2row + kb + 4);
        float4 eb0 = *(const float4*)(e1 + kb);
        float4 eb1 = *(const float4*)(e1 + kb + 4);
        short8 af;
        af[0] = (short)f2bf(ea0.x * eb0.x);
        af[1] = (short)f2bf(ea0.y * eb0.y);
        af[2] = (short)f2bf(ea0.z * eb0.z);
        af[3] = (short)f2bf(ea0.w * eb0.w);
        af[4] = (short)f2bf(ea1.x * eb1.x);
        af[5] = (short)f2bf(ea1.y * eb1.y);
        af[6] = (short)f2bf(ea1.z * eb1.z);
        af[7] = (short)f2bf(ea1.w * eb1.w);
        __syncthreads();   // staging visible
        const short8* bst = (const short8*)Bst;
#pragma unroll
        for (int tt = 0; tt < 16; ++tt) {
            short8 bfr = bst[tt * 64 + lane];
            acc[tt] = __builtin_amdgcn_mfma_f32_16x16x32_bf16(af, bfr, acc[tt], 0, 0, 0);
        }
    }

    // ----- add comb + A2; LayerNorm per row (row = jbase + q*4 + r, cols spread over lanes of quad) -----
    float s1[4] = {0.f, 0.f, 0.f, 0.f}, s2[4] = {0.f, 0.f, 0.f, 0.f};
#pragma unroll
    for (int tt = 0; tt < 16; ++tt) {
        int col = tt * 16 + n;
        float cb = comb[col];
#pragma unroll
        for (int r = 0; r < 4; ++r) {
            int jr = jbase + q * 4 + r;
            float v = acc[tt][r] + cb + A2[(size_t)jr * 256 + col];
            acc[tt][r] = v;
            s1[r] += v;
            s2[r] += v * v;
        }
    }
#pragma unroll
    for (int off = 1; off < 16; off <<= 1) {
#pragma unroll
        for (int r = 0; r < 4; ++r) {
            s1[r] += __shfl_xor(s1[r], off);
            s2[r] += __shfl_xor(s2[r], off);
        }
    }
    float mean[4], rstd[4];
#pragma unroll
    for (int r = 0; r < 4; ++r) {
        mean[r] = s1[r] * (1.f / 256.f);
        float var = s2[r] * (1.f / 256.f) - mean[r] * mean[r];
        rstd[r] = rsqrtf(var + 1e-5f);
    }
    ushort* hrow = Hs[w];
#pragma unroll
    for (int tt = 0; tt < 16; ++tt) {
        int col = tt * 16 + n;
        float gg = g3s[col], be = be3s[col];
#pragma unroll
        for (int r = 0; r < 4; ++r) {
            float hv = fmaxf((acc[tt][r] - mean[r]) * rstd[r] * gg + be, 0.f);
            hrow[(q * 4 + r) * 264 + col] = f2bf(hv);
        }
    }
    // Hs[w] is per-wave; the syncthreads at top of the GEMM2 loop drains lgkmcnt.

    // ----- GEMM2: G = H @ W4 -----
    f32x4 gacc[8];
#pragma unroll
    for (int x = 0; x < 8; ++x) gacc[x] = (f32x4){0.f, 0.f, 0.f, 0.f};

    for (int kk = 0; kk < 8; ++kk) {
        __syncthreads();   // prior Bst reads done
        {
            const uint4* src = (const uint4*)(W4p + (size_t)kk * 4096);
#pragma unroll
            for (int x = 0; x < 2; ++x) Bst[t * 2 + x] = src[t * 2 + x];
        }
        short8 af = *(const short8*)(hrow + n * 264 + kk * 32 + q * 8);
        __syncthreads();
        const short8* bst = (const short8*)Bst;
#pragma unroll
        for (int tt = 0; tt < 8; ++tt) {
            short8 bfr = bst[tt * 64 + lane];
            gacc[tt] = __builtin_amdgcn_mfma_f32_16x16x32_bf16(af, bfr, gacc[tt], 0, 0, 0);
        }
    }

    // ----- epilogue: E[i,j] = relu(G + b4) . W5 + b5 -----
    float ep[4] = {0.f, 0.f, 0.f, 0.f};
    float b5v = b5[0];
#pragma unroll
    for (int tt = 0; tt < 8; ++tt) {
        int col = tt * 16 + n;
        float b4v = b4[col], w5v = W5[col];
#pragma unroll
        for (int r = 0; r < 4; ++r)
            ep[r] += fmaxf(gacc[tt][r] + b4v, 0.f) * w5v;
    }
#pragma unroll
    for (int off = 1; off < 16; off <<= 1) {
#pragma unroll
        for (int r = 0; r < 4; ++r) ep[r] += __shfl_xor(ep[r], off);
    }
    if (n == 0) {
#pragma unroll
        for (int r = 0; r < 4; ++r)
            E[(size_t)i * 256 + jbase + q * 4 + r] = ep[r] + b5v;
    }
}

// ---------------- margin loss ----------------
__global__ void margin_kernel(const float* __restrict__ E, float* slAcc) {
    __shared__ float red[4];
    int i = blockIdx.x, t = threadIdx.x;
    float diag = E[(size_t)i * 256 + i];
    float l = (t == i) ? 0.f : fmaxf(1.f + E[(size_t)i * 256 + t] - diag, 0.f);
    float tot = block_sum256(l, red);
    if (t == 0) atomicAdd(slAcc, tot);
}

// ---------------- finalize ----------------
__global__ void finalize_kernel(const float* wsf, float* out) {
    if (threadIdx.x == 0 && blockIdx.x == 0) {
        float recon = wsf[0] / 3145728.f;
        float sp = 0.5f * (wsf[1] / 4194304.f + wsf[2] / 2097152.f);
        float en = 0.5f * (wsf[3] + wsf[4]);
        float compress = sp + 0.1f * en;
        float sl = wsf[5] / (256.f * 255.f);
        float nl = 1.f - wsf[6] / 256.f;
        float energy = sl + 0.3f * nl;
        float total = recon + 0.01f * compress + 0.1f * energy;
        out[0] = total;
        out[1] = recon;
        out[2] = energy;
        out[3] = compress;
    }
}

// ---------------- launch ----------------
extern "C" void kernel_launch(void* const* d_in, const int* in_sizes, int n_in,
                              void* d_out, int out_size, void* d_ws, size_t ws_size,
                              hipStream_t stream) {
    const float* outputs = (const float*)d_in[0];
    const float* images  = (const float*)d_in[1];
    const float* f_orig  = (const float*)d_in[2];
    const float* f_recon = (const float*)d_in[3];
    const float* cf1 = (const float*)d_in[4];
    const float* cf2 = (const float*)d_in[5];
    const float* W1 = (const float*)d_in[6];
    const float* b1 = (const float*)d_in[7];
    const float* g1 = (const float*)d_in[8];
    const float* be1 = (const float*)d_in[9];
    const float* W2 = (const float*)d_in[10];
    const float* b2 = (const float*)d_in[11];
    const float* W3 = (const float*)d_in[12];
    const float* b3 = (const float*)d_in[13];
    const float* g3 = (const float*)d_in[14];
    const float* be3 = (const float*)d_in[15];
    const float* W4 = (const float*)d_in[16];
    const float* b4 = (const float*)d_in[17];
    const float* W5 = (const float*)d_in[18];
    const float* b5 = (const float*)d_in[19];

    float* wsf = (float*)d_ws;
    unsigned* wsu = (unsigned*)d_ws;
    int* wsi = (int*)d_ws;
    float* out = (float*)d_out;

    float* rnorm = wsf + 528;
    float* eAll = wsf + 1040;
    float* Aall = wsf + 132112;
    float* Emat = wsf + 263184;
    ushort* W3pk = (ushort*)(wsf + 328720);
    ushort* W4pk = (ushort*)(wsf + 361488);

    hipLaunchKernelGGL(init_kernel, dim3(1), dim3(256), 0, stream, wsf, wsu, wsi);
    hipLaunchKernelGGL(pack_w3_kernel, dim3(32), dim3(256), 0, stream, W3 + 512 * 256, W3pk);
    hipLaunchKernelGGL(pack_w4_kernel, dim3(16), dim3(256), 0, stream, W4, W4pk);
    hipLaunchKernelGGL(recon_kernel, dim3(512), dim3(256), 0, stream,
                       (const float4*)outputs, (const float4*)images, 786432, wsf + 0);
    hipLaunchKernelGGL(absmm_kernel, dim3(512), dim3(256), 0, stream,
                       (const float4*)cf1, 1048576, wsf + 1, wsu + 7, wsu + 8);
    hipLaunchKernelGGL(absmm_kernel, dim3(512), dim3(256), 0, stream,
                       (const float4*)cf2, 524288, wsf + 2, wsu + 9, wsu + 10);
    hipLaunchKernelGGL(hist_kernel, dim3(512), dim3(256), 0, stream,
                       (const float4*)cf1, 1048576, wsu + 7, wsi + 16);
    hipLaunchKernelGGL(hist_kernel, dim3(512), dim3(256), 0, stream,
                       (const float4*)cf2, 524288, wsu + 9, wsi + 272);
    hipLaunchKernelGGL(entropy_kernel, dim3(1), dim3(256), 0, stream,
                       wsi + 16, wsi + 272, wsf + 3, 4194304.f, 2097152.f);
    hipLaunchKernelGGL(norm_kernel, dim3(512), dim3(256), 0, stream,
                       (const float4*)f_orig, (const float4*)f_recon, rnorm);
    hipLaunchKernelGGL(encoder_kernel, dim3(512), dim3(256), 0, stream,
                       f_orig, f_recon, W1, b1, g1, be1, W2, b2, W3, eAll, Aall);
    hipLaunchKernelGGL(topk_kernel, dim3(256), dim3(256), 0, stream,
                       (const float4*)f_orig, (const float4*)f_recon, rnorm, wsf + 6);
    hipLaunchKernelGGL(energy_mfma_kernel, dim3(1024), dim3(256), 0, stream,
                       eAll, Aall, W3pk, W4pk, b3, g3, be3, b4, W5, b5, Emat);
    hipLaunchKernelGGL(margin_kernel, dim3(256), dim3(256), 0, stream, Emat, wsf + 5);
    hipLaunchKernelGGL(finalize_kernel, dim3(1), dim3(1), 0, stream, wsf, out);
}

// Round 3
// 278.189 us; speedup vs baseline: 2.6622x; 1.1631x over previous
//
#include <hip/hip_runtime.h>
#include <math.h>

typedef __attribute__((ext_vector_type(8))) short short8;
typedef __attribute__((ext_vector_type(4))) float f32x4;

// ---------------- helpers ----------------

__device__ __forceinline__ float wave_sum(float v) {
#pragma unroll
    for (int o = 32; o > 0; o >>= 1) v += __shfl_down(v, o);
    return v;
}

// blockDim.x == 256 only
__device__ __forceinline__ float block_sum256(float v, float* red) {
    v = wave_sum(v);
    int t = threadIdx.x;
    if ((t & 63) == 0) red[t >> 6] = v;
    __syncthreads();
    float r = red[0] + red[1] + red[2] + red[3];
    __syncthreads();
    return r;
}

__device__ __forceinline__ unsigned fenc(float f) {
    unsigned u = __float_as_uint(f);
    return (u & 0x80000000u) ? ~u : (u | 0x80000000u);
}
__device__ __forceinline__ float fdec(unsigned u) {
    return (u & 0x80000000u) ? __uint_as_float(u & 0x7fffffffu) : __uint_as_float(~u);
}

__device__ __forceinline__ ushort f2bf(float f) {
    unsigned u = __float_as_uint(f);
    unsigned r = (u + 0x7fffu + ((u >> 16) & 1u)) >> 16;
    return (ushort)r;
}

// ---------------- ws float layout ----------------
// 0 recon_sum, 1 abs1, 2 abs2, 5 sl_sum, 6 jac_sum
// 7 min1(u),8 max1(u),9 min2(u),10 max2(u)
// 16..271 hist1(int), 272..527 hist2(int)
// 528 rnorm[512] -> 1040
// 1040 eAll[131072] -> 132112
// 132112 Aall[131072] -> 263184
// 263184 Emat[65536] -> 328720
// 328720 W3pk (32768 floats) -> 361488
// 361488 W4pk (16384 floats) -> 377872
// 377872 fnT[2*512*256] -> 640016
// 640016 top5 ints[2*256*5] -> 642576

__global__ void init_kernel(float* wsf, unsigned* wsu, int* wsi) {
    int t = threadIdx.x;
    if (t < 7) wsf[t] = 0.f;
    if (t == 7 || t == 9) wsu[t] = 0xFFFFFFFFu;   // mins
    if (t == 8 || t == 10) wsu[t] = 0u;           // maxs
    wsi[16 + t] = 0;
    wsi[272 + t] = 0;
}

// ---------------- merged stats: recon + absmm(cf1) + absmm(cf2) + norms ----------------
__global__ __launch_bounds__(256) void stats_kernel(
    const float4* __restrict__ o, const float4* __restrict__ im,
    const float4* __restrict__ cf1, const float4* __restrict__ cf2,
    const float4* __restrict__ fo, const float4* __restrict__ fr,
    float* wsf, unsigned* wsu, float* rnorm) {
    __shared__ float red[4];
    __shared__ float rmn[4], rmx[4];
    int b = blockIdx.x, t = threadIdx.x;
    if (b < 512) {
        // recon: sum (o-im)^2 over 786432 float4
        float s = 0.f;
        for (int i = b * 256 + t; i < 786432; i += 512 * 256) {
            float4 a = o[i], c = im[i];
            float dx = a.x - c.x, dy = a.y - c.y, dz = a.z - c.z, dw = a.w - c.w;
            s += dx * dx + dy * dy + dz * dz + dw * dw;
        }
        float tot = block_sum256(s, red);
        if (t == 0) atomicAdd(wsf + 0, tot);
    } else if (b < 1536) {
        // absmm over cf1 (blocks 512..1023) or cf2 (1024..1535)
        int which = (b < 1024) ? 0 : 1;
        const float4* x = which ? cf2 : cf1;
        int n4 = which ? 524288 : 1048576;
        int b0 = which ? 1024 : 512;
        float s = 0.f, mn = INFINITY, mx = -INFINITY;
        for (int i = (b - b0) * 256 + t; i < n4; i += 512 * 256) {
            float4 a = x[i];
            s += fabsf(a.x) + fabsf(a.y) + fabsf(a.z) + fabsf(a.w);
            mn = fminf(mn, fminf(fminf(a.x, a.y), fminf(a.z, a.w)));
            mx = fmaxf(mx, fmaxf(fmaxf(a.x, a.y), fmaxf(a.z, a.w)));
        }
        float tot = block_sum256(s, red);
#pragma unroll
        for (int off = 32; off > 0; off >>= 1) {
            mn = fminf(mn, __shfl_down(mn, off));
            mx = fmaxf(mx, __shfl_down(mx, off));
        }
        if ((t & 63) == 0) { rmn[t >> 6] = mn; rmx[t >> 6] = mx; }
        __syncthreads();
        if (t == 0) {
            atomicAdd(wsf + 1 + which, tot);
            float m1 = fminf(fminf(rmn[0], rmn[1]), fminf(rmn[2], rmn[3]));
            float m2 = fmaxf(fmaxf(rmx[0], rmx[1]), fmaxf(rmx[2], rmx[3]));
            atomicMin(wsu + 7 + which * 2, fenc(m1));
            atomicMax(wsu + 8 + which * 2, fenc(m2));
        }
    } else {
        // row norms: r = b - 1536 in [0,512)
        int r = b - 1536;
        const float4* f = (r < 256) ? (fo + (size_t)r * 128) : (fr + (size_t)(r - 256) * 128);
        float s = 0.f;
        if (t < 128) {
            float4 a = f[t];
            s = a.x * a.x + a.y * a.y + a.z * a.z + a.w * a.w;
        }
        float tot = block_sum256(s, red);
        if (t == 0) rnorm[r] = 1.0f / sqrtf(tot);
    }
}

// ---------------- merged histogram ----------------
__global__ __launch_bounds__(256) void hist_kernel(const float4* __restrict__ cf1,
                                                   const float4* __restrict__ cf2,
                                                   const unsigned* wsu, int* wsi) {
    __shared__ int hl[256];
    int b = blockIdx.x, t = threadIdx.x;
    hl[t] = 0;
    __syncthreads();
    int which = (b < 512) ? 0 : 1;
    const float4* x = which ? cf2 : cf1;
    int n4 = which ? 524288 : 1048576;
    int b0 = which ? 512 : 0;
    int* hist = wsi + (which ? 272 : 16);
    float mn = fdec(wsu[7 + which * 2]), mx = fdec(wsu[8 + which * 2]);
    float inv = 256.f / (mx - mn + 1e-8f);
    for (int i = (b - b0) * 256 + t; i < n4; i += 512 * 256) {
        float4 a = x[i];
        int b0i = min(max((int)floorf((a.x - mn) * inv), 0), 255);
        int b1i = min(max((int)floorf((a.y - mn) * inv), 0), 255);
        int b2i = min(max((int)floorf((a.z - mn) * inv), 0), 255);
        int b3i = min(max((int)floorf((a.w - mn) * inv), 0), 255);
        atomicAdd(&hl[b0i], 1);
        atomicAdd(&hl[b1i], 1);
        atomicAdd(&hl[b2i], 1);
        atomicAdd(&hl[b3i], 1);
    }
    __syncthreads();
    if (hl[t]) atomicAdd(&hist[t], hl[t]);
}

// ---------------- transpose: fnT[pass][k][j] = f[j][k]*rnorm[j] ----------------
__global__ __launch_bounds__(256) void transpose_kernel(const float* __restrict__ fo,
                                                        const float* __restrict__ fr,
                                                        const float* __restrict__ rnorm,
                                                        float* __restrict__ fnT) {
    // grid 128: b = pass*64 + kt*4 + jt
    int b = blockIdx.x;
    int pass = b >> 6;
    int kt = (b >> 2) & 15;
    int jt = b & 3;
    int k0 = kt * 32, j0 = jt * 64;
    const float* f = pass ? fr : fo;
    const float* rn = rnorm + pass * 256;
    __shared__ float tile[64][33];
    int t = threadIdx.x;
    int cl = t & 31, rl = t >> 5;  // rl 0..7
#pragma unroll
    for (int r = 0; r < 8; ++r) {
        int row = j0 + rl + r * 8;
        tile[rl + r * 8][cl] = f[(size_t)row * 512 + k0 + cl] * rn[row];
    }
    __syncthreads();
    int jl = t & 63, kq = t >> 6;  // kq 0..3
    float* dst = fnT + (size_t)pass * 131072;
#pragma unroll
    for (int c = 0; c < 8; ++c) {
        int kl = kq * 8 + c;
        dst[(size_t)(k0 + kl) * 256 + j0 + jl] = tile[jl][kl];
    }
}

// ---------------- fused sim + top5 (per i-pair), wave-level selection ----------------
__global__ __launch_bounds__(256) void simtop_kernel(const float* __restrict__ fo,
                                                     const float* __restrict__ fr,
                                                     const float* __restrict__ rnorm,
                                                     const float* __restrict__ fnT,
                                                     int* __restrict__ top5) {
    int b = blockIdx.x;
    int pass = b >> 7, pair = b & 127;
    int i0 = pair * 2, i1 = i0 + 1;
    const float* f = pass ? fr : fo;
    const float* rn = rnorm + pass * 256;
    __shared__ float2 fs2[512];
    __shared__ float candV[4][2][5];
    __shared__ int candI[4][2][5];
    int t = threadIdx.x;
    float rn0 = rn[i0], rn1 = rn[i1];
    const float* f0 = f + (size_t)i0 * 512;
    const float* f1 = f + (size_t)i1 * 512;
    fs2[t] = make_float2(f0[t] * rn0, f1[t] * rn1);
    fs2[t + 256] = make_float2(f0[t + 256] * rn0, f1[t + 256] * rn1);
    __syncthreads();
    int j = t;  // wave w covers j in [w*64, w*64+64)
    const float* col = fnT + (size_t)pass * 131072 + j;
    float a0 = 0.f, a1 = 0.f;
#pragma unroll 16
    for (int k = 0; k < 512; ++k) {
        float v = col[(size_t)k * 256];
        float2 fv = fs2[k];
        a0 += fv.x * v;
        a1 += fv.y * v;
    }
    if (j == i0) a0 = -INFINITY;
    if (j == i1) a1 = -INFINITY;
    int w = t >> 6, lane = t & 63;
    // per-wave top5 for each of the two i's (no barriers: shfl butterflies)
    for (int sel = 0; sel < 2; ++sel) {
        float v2 = sel ? a1 : a0;
        int idx = j;
        for (int r = 0; r < 5; ++r) {
            float m = v2;
            int mi = idx;
#pragma unroll
            for (int off = 32; off > 0; off >>= 1) {
                float om = __shfl_xor(m, off);
                int omi = __shfl_xor(mi, off);
                if (om > m || (om == m && omi < mi)) { m = om; mi = omi; }
            }
            if (lane == 0) { candV[w][sel][r] = m; candI[w][sel][r] = mi; }
            if (idx == mi) v2 = -INFINITY;
        }
    }
    __syncthreads();
    // merge 20 candidates: wave 0 -> i0, wave 1 -> i1
    if (w < 2) {
        float v = -INFINITY;
        int ix = 0x7fffffff;
        if (lane < 20) { v = candV[lane / 5][w][lane % 5]; ix = candI[lane / 5][w][lane % 5]; }
        int iSel = w ? i1 : i0;
        for (int r = 0; r < 5; ++r) {
            float m = v;
            int mi = ix;
#pragma unroll
            for (int off = 32; off > 0; off >>= 1) {
                float om = __shfl_xor(m, off);
                int omi = __shfl_xor(mi, off);
                if (om > m || (om == m && omi < mi)) { m = om; mi = omi; }
            }
            if (lane == 0) top5[((size_t)pass * 256 + iSel) * 5 + r] = mi;
            if (ix == mi) v = -INFINITY;
        }
    }
}

// ---------------- jaccard from top5 sets ----------------
__global__ void jaccard_kernel(const int* __restrict__ top5, float* jacOut) {
    __shared__ float red[4];
    int i = threadIdx.x;
    int O[5], R[5];
#pragma unroll
    for (int r = 0; r < 5; ++r) {
        O[r] = top5[i * 5 + r];
        R[r] = top5[(256 + i) * 5 + r];
    }
    int inter = 0;
#pragma unroll
    for (int a = 0; a < 5; ++a)
#pragma unroll
        for (int bq = 0; bq < 5; ++bq) inter += (O[a] == R[bq]);
    float fi2 = (float)inter;
    float jac = fi2 / (10.f - fi2 + 1e-8f);
    float s = block_sum256(jac, red);
    if (i == 0) jacOut[0] = s;
}

// ---------------- encoder: e = relu(LN(f@W1+b1))@W2+b2 ; A = e @ W3part ----------------
__global__ void encoder_kernel(const float* __restrict__ f_orig, const float* __restrict__ f_recon,
                               const float* __restrict__ W1, const float* __restrict__ b1,
                               const float* __restrict__ g1, const float* __restrict__ be1,
                               const float* __restrict__ W2, const float* __restrict__ b2,
                               const float* __restrict__ W3,
                               float* __restrict__ eAll, float* __restrict__ Aall) {
    int r = blockIdx.x;  // 0..511
    int t = threadIdx.x; // 0..255
    const float* f = (r < 256) ? (f_orig + (size_t)r * 512) : (f_recon + (size_t)(r - 256) * 512);
    const float* W3p = (r < 256) ? W3 : (W3 + 256 * 256);
    __shared__ float fs[512];
    __shared__ float hs[256];
    __shared__ float es[256];
    __shared__ float red[4];
    fs[t] = f[t];
    fs[t + 256] = f[t + 256];
    __syncthreads();
    float x = b1[t];
    for (int k = 0; k < 512; ++k) x += fs[k] * W1[k * 256 + t];
    float s1 = block_sum256(x, red);
    float s2 = block_sum256(x * x, red);
    float mean = s1 * (1.f / 256.f);
    float var = s2 * (1.f / 256.f) - mean * mean;
    float rstd = rsqrtf(var + 1e-5f);
    float hn = (x - mean) * rstd * g1[t] + be1[t];
    hs[t] = fmaxf(hn, 0.f);
    __syncthreads();
    float e = b2[t];
    for (int k = 0; k < 256; ++k) e += hs[k] * W2[k * 256 + t];
    eAll[(size_t)r * 256 + t] = e;
    es[t] = e;
    __syncthreads();
    float a = 0.f;
    for (int k = 0; k < 256; ++k) a += es[k] * W3p[k * 256 + t];
    Aall[(size_t)r * 256 + t] = a;
}

// ---------------- pack W3c / W4 into bf16 B-fragment order ----------------
__global__ void pack_kernel(const float* __restrict__ W3c, const float* __restrict__ W4,
                            ushort* __restrict__ W3p, ushort* __restrict__ W4p) {
    int b = blockIdx.x, t = threadIdx.x;
    if (b < 32) {
        int s = b * 256 + t;   // 0..8191
        int lane = s & 63;
        int tt = (s >> 6) & 15;
        int kk = s >> 10;
        int qq = lane >> 4, nn = lane & 15;
        int tcol = tt * 16 + nn;
        short8 v;
#pragma unroll
        for (int jj = 0; jj < 8; ++jj) {
            int k = kk * 32 + qq * 8 + jj;
            v[jj] = (short)f2bf(W3c[(size_t)k * 256 + tcol]);
        }
        *(short8*)(W3p + (size_t)s * 8) = v;
    } else {
        int s = (b - 32) * 256 + t;  // 0..4095
        int lane = s & 63;
        int tt = (s >> 6) & 7;
        int kk = s >> 9;
        int qq = lane >> 4, nn = lane & 15;
        int ncol = tt * 16 + nn;
        short8 v;
#pragma unroll
        for (int jj = 0; jj < 8; ++jj) {
            int k = kk * 32 + qq * 8 + jj;
            v[jj] = (short)f2bf(W4[(size_t)k * 128 + ncol]);
        }
        *(short8*)(W4p + (size_t)s * 8) = v;
    }
}

// ---------------- energy pairs via MFMA ----------------
__global__ __launch_bounds__(256) void energy_mfma_kernel(
    const float* __restrict__ eAll, const float* __restrict__ Aall,
    const ushort* __restrict__ W3p, const ushort* __restrict__ W4p,
    const float* __restrict__ b3, const float* __restrict__ g3, const float* __restrict__ be3,
    const float* __restrict__ b4, const float* __restrict__ W5, const float* __restrict__ b5,
    float* __restrict__ E)
{
    int i = blockIdx.x >> 2;
    int jq = blockIdx.x & 3;
    int t = threadIdx.x;
    int w = t >> 6;
    int lane = t & 63;
    int q = lane >> 4;
    int n = lane & 15;
    int jbase = jq * 64 + w * 16;

    __shared__ float comb[256], g3s[256], be3s[256];
    __shared__ uint4 Bst[1024];                        // 16 KB staging buffer
    __shared__ __align__(16) ushort Hs[4][16 * 264];   // per-wave H, padded stride

    const float* e1 = eAll + (size_t)i * 256;
    const float* e2 = eAll + 65536;
    const float* A1 = Aall + (size_t)i * 256;
    const float* A2 = Aall + 65536;

    comb[t] = A1[t] + b3[t];
    g3s[t] = g3[t];
    be3s[t] = be3[t];

    f32x4 acc[16];
#pragma unroll
    for (int x = 0; x < 16; ++x) acc[x] = (f32x4){0.f, 0.f, 0.f, 0.f};

    const float* e2row = e2 + (size_t)(jbase + n) * 256;   // A-frag row (m = lane&15)

    for (int kk = 0; kk < 8; ++kk) {
        __syncthreads();   // prior Bst reads done (also covers comb/g3s on first iter)
        {
            const uint4* src = (const uint4*)(W3p + (size_t)kk * 8192);
#pragma unroll
            for (int x = 0; x < 4; ++x) Bst[t * 4 + x] = src[t * 4 + x];
        }
        int kb = kk * 32 + q * 8;
        float4 ea0 = *(const float4*)(e2row + kb);
        float4 ea1 = *(const float4*)(e2row + kb + 4);
        float4 eb0 = *(const float4*)(e1 + kb);
        float4 eb1 = *(const float4*)(e1 + kb + 4);
        short8 af;
        af[0] = (short)f2bf(ea0.x * eb0.x);
        af[1] = (short)f2bf(ea0.y * eb0.y);
        af[2] = (short)f2bf(ea0.z * eb0.z);
        af[3] = (short)f2bf(ea0.w * eb0.w);
        af[4] = (short)f2bf(ea1.x * eb1.x);
        af[5] = (short)f2bf(ea1.y * eb1.y);
        af[6] = (short)f2bf(ea1.z * eb1.z);
        af[7] = (short)f2bf(ea1.w * eb1.w);
        __syncthreads();   // staging visible
        const short8* bst = (const short8*)Bst;
#pragma unroll
        for (int tt = 0; tt < 16; ++tt) {
            short8 bfr = bst[tt * 64 + lane];
            acc[tt] = __builtin_amdgcn_mfma_f32_16x16x32_bf16(af, bfr, acc[tt], 0, 0, 0);
        }
    }

    // ----- add comb + A2; LayerNorm per row -----
    float s1[4] = {0.f, 0.f, 0.f, 0.f}, s2[4] = {0.f, 0.f, 0.f, 0.f};
#pragma unroll
    for (int tt = 0; tt < 16; ++tt) {
        int col = tt * 16 + n;
        float cb = comb[col];
#pragma unroll
        for (int r = 0; r < 4; ++r) {
            int jr = jbase + q * 4 + r;
            float v = acc[tt][r] + cb + A2[(size_t)jr * 256 + col];
            acc[tt][r] = v;
            s1[r] += v;
            s2[r] += v * v;
        }
    }
#pragma unroll
    for (int off = 1; off < 16; off <<= 1) {
#pragma unroll
        for (int r = 0; r < 4; ++r) {
            s1[r] += __shfl_xor(s1[r], off);
            s2[r] += __shfl_xor(s2[r], off);
        }
    }
    float mean[4], rstd[4];
#pragma unroll
    for (int r = 0; r < 4; ++r) {
        mean[r] = s1[r] * (1.f / 256.f);
        float var = s2[r] * (1.f / 256.f) - mean[r] * mean[r];
        rstd[r] = rsqrtf(var + 1e-5f);
    }
    ushort* hrow = Hs[w];
#pragma unroll
    for (int tt = 0; tt < 16; ++tt) {
        int col = tt * 16 + n;
        float gg = g3s[col], be = be3s[col];
#pragma unroll
        for (int r = 0; r < 4; ++r) {
            float hv = fmaxf((acc[tt][r] - mean[r]) * rstd[r] * gg + be, 0.f);
            hrow[(q * 4 + r) * 264 + col] = f2bf(hv);
        }
    }

    // ----- GEMM2: G = H @ W4 -----
    f32x4 gacc[8];
#pragma unroll
    for (int x = 0; x < 8; ++x) gacc[x] = (f32x4){0.f, 0.f, 0.f, 0.f};

    for (int kk = 0; kk < 8; ++kk) {
        __syncthreads();   // prior Bst reads done + Hs lgkm drain
        {
            const uint4* src = (const uint4*)(W4p + (size_t)kk * 4096);
#pragma unroll
            for (int x = 0; x < 2; ++x) Bst[t * 2 + x] = src[t * 2 + x];
        }
        short8 af = *(const short8*)(hrow + n * 264 + kk * 32 + q * 8);
        __syncthreads();
        const short8* bst = (const short8*)Bst;
#pragma unroll
        for (int tt = 0; tt < 8; ++tt) {
            short8 bfr = bst[tt * 64 + lane];
            gacc[tt] = __builtin_amdgcn_mfma_f32_16x16x32_bf16(af, bfr, gacc[tt], 0, 0, 0);
        }
    }

    // ----- epilogue: E[i,j] = relu(G + b4) . W5 + b5 -----
    float ep[4] = {0.f, 0.f, 0.f, 0.f};
    float b5v = b5[0];
#pragma unroll
    for (int tt = 0; tt < 8; ++tt) {
        int col = tt * 16 + n;
        float b4v = b4[col], w5v = W5[col];
#pragma unroll
        for (int r = 0; r < 4; ++r)
            ep[r] += fmaxf(gacc[tt][r] + b4v, 0.f) * w5v;
    }
#pragma unroll
    for (int off = 1; off < 16; off <<= 1) {
#pragma unroll
        for (int r = 0; r < 4; ++r) ep[r] += __shfl_xor(ep[r], off);
    }
    if (n == 0) {
#pragma unroll
        for (int r = 0; r < 4; ++r)
            E[(size_t)i * 256 + jbase + q * 4 + r] = ep[r] + b5v;
    }
}

// ---------------- margin loss ----------------
__global__ void margin_kernel(const float* __restrict__ E, float* slAcc) {
    __shared__ float red[4];
    int i = blockIdx.x, t = threadIdx.x;
    float diag = E[(size_t)i * 256 + i];
    float l = (t == i) ? 0.f : fmaxf(1.f + E[(size_t)i * 256 + t] - diag, 0.f);
    float tot = block_sum256(l, red);
    if (t == 0) atomicAdd(slAcc, tot);
}

// ---------------- finalize (with fused entropy) ----------------
__global__ void finalize_kernel(const float* wsf, const int* h1, const int* h2, float* out) {
    __shared__ float red[4];
    int t = threadIdx.x;
    float p1 = (float)h1[t] / 4194304.f;
    float p2 = (float)h2[t] / 2097152.f;
    float s1 = block_sum256(-p1 * log2f(p1 + 1e-8f), red);
    float s2 = block_sum256(-p2 * log2f(p2 + 1e-8f), red);
    if (t == 0) {
        float recon = wsf[0] / 3145728.f;
        float sp = 0.5f * (wsf[1] / 4194304.f + wsf[2] / 2097152.f);
        float en = 0.5f * (s1 + s2);
        float compress = sp + 0.1f * en;
        float sl = wsf[5] / (256.f * 255.f);
        float nl = 1.f - wsf[6] / 256.f;
        float energy = sl + 0.3f * nl;
        float total = recon + 0.01f * compress + 0.1f * energy;
        out[0] = total;
        out[1] = recon;
        out[2] = energy;
        out[3] = compress;
    }
}

// ---------------- launch ----------------
extern "C" void kernel_launch(void* const* d_in, const int* in_sizes, int n_in,
                              void* d_out, int out_size, void* d_ws, size_t ws_size,
                              hipStream_t stream) {
    const float* outputs = (const float*)d_in[0];
    const float* images  = (const float*)d_in[1];
    const float* f_orig  = (const float*)d_in[2];
    const float* f_recon = (const float*)d_in[3];
    const float* cf1 = (const float*)d_in[4];
    const float* cf2 = (const float*)d_in[5];
    const float* W1 = (const float*)d_in[6];
    const float* b1 = (const float*)d_in[7];
    const float* g1 = (const float*)d_in[8];
    const float* be1 = (const float*)d_in[9];
    const float* W2 = (const float*)d_in[10];
    const float* b2 = (const float*)d_in[11];
    const float* W3 = (const float*)d_in[12];
    const float* b3 = (const float*)d_in[13];
    const float* g3 = (const float*)d_in[14];
    const float* be3 = (const float*)d_in[15];
    const float* W4 = (const float*)d_in[16];
    const float* b4 = (const float*)d_in[17];
    const float* W5 = (const float*)d_in[18];
    const float* b5 = (const float*)d_in[19];

    float* wsf = (float*)d_ws;
    unsigned* wsu = (unsigned*)d_ws;
    int* wsi = (int*)d_ws;
    float* out = (float*)d_out;

    float* rnorm = wsf + 528;
    float* eAll = wsf + 1040;
    float* Aall = wsf + 132112;
    float* Emat = wsf + 263184;
    ushort* W3pk = (ushort*)(wsf + 328720);
    ushort* W4pk = (ushort*)(wsf + 361488);
    float* fnT = wsf + 377872;
    int* top5 = wsi + 640016;

    hipLaunchKernelGGL(init_kernel, dim3(1), dim3(256), 0, stream, wsf, wsu, wsi);
    hipLaunchKernelGGL(pack_kernel, dim3(48), dim3(256), 0, stream,
                       W3 + 512 * 256, W4, W3pk, W4pk);
    hipLaunchKernelGGL(stats_kernel, dim3(2048), dim3(256), 0, stream,
                       (const float4*)outputs, (const float4*)images,
                       (const float4*)cf1, (const float4*)cf2,
                       (const float4*)f_orig, (const float4*)f_recon,
                       wsf, wsu, rnorm);
    hipLaunchKernelGGL(hist_kernel, dim3(1024), dim3(256), 0, stream,
                       (const float4*)cf1, (const float4*)cf2, wsu, wsi);
    hipLaunchKernelGGL(transpose_kernel, dim3(128), dim3(256), 0, stream,
                       f_orig, f_recon, rnorm, fnT);
    hipLaunchKernelGGL(encoder_kernel, dim3(512), dim3(256), 0, stream,
                       f_orig, f_recon, W1, b1, g1, be1, W2, b2, W3, eAll, Aall);
    hipLaunchKernelGGL(simtop_kernel, dim3(256), dim3(256), 0, stream,
                       f_orig, f_recon, rnorm, fnT, top5);
    hipLaunchKernelGGL(energy_mfma_kernel, dim3(1024), dim3(256), 0, stream,
                       eAll, Aall, W3pk, W4pk, b3, g3, be3, b4, W5, b5, Emat);
    hipLaunchKernelGGL(margin_kernel, dim3(256), dim3(256), 0, stream, Emat, wsf + 5);
    hipLaunchKernelGGL(jaccard_kernel, dim3(1), dim3(256), 0, stream, top5, wsf + 6);
    hipLaunchKernelGGL(finalize_kernel, dim3(1), dim3(256), 0, stream,
                       wsf, wsi + 16, wsi + 272, out);
}